// Round 1
// baseline (9030.293 us; speedup 1.0000x reference)
//
#include <hip/hip_runtime.h>
#include <stdint.h>

typedef unsigned short ushort_t;
typedef __attribute__((ext_vector_type(8))) short bf16x8;
typedef __attribute__((ext_vector_type(8))) unsigned short u16x8;
typedef __attribute__((ext_vector_type(4))) unsigned short u16x4;
typedef __attribute__((ext_vector_type(4))) float f32x4;

#define DEV static __device__ __forceinline__

DEV unsigned short f2bf(float f) {           // fp32 -> bf16 RNE
  unsigned u = __float_as_uint(f);
  u += 0x7FFFu + ((u >> 16) & 1u);
  return (unsigned short)(u >> 16);
}
DEV float bf2f(unsigned short h) { return __uint_as_float(((unsigned)h) << 16); }
DEV float fast_rcp(float x) { return __builtin_amdgcn_rcpf(x); }
DEV float fast_tanh(float x) { float e = __expf(2.f * x); return (e - 1.f) * fast_rcp(e + 1.f); }
DEV float fast_sigm(float x) { return fast_rcp(1.f + __expf(-x)); }

DEV float wave_sum(float v) {
#pragma unroll
  for (int d = 32; d > 0; d >>= 1) v += __shfl_xor(v, d, 64);
  return v;
}
DEV float wave_max(float v) {
#pragma unroll
  for (int d = 32; d > 0; d >>= 1) v = fmaxf(v, __shfl_xor(v, d, 64));
  return v;
}

DEV void async_g2l(const void* g, void* l) {   // 16B global -> LDS (dest = uniform base + lane*16)
  __builtin_amdgcn_global_load_lds((const __attribute__((address_space(1))) void*)g,
                                   (__attribute__((address_space(3))) void*)l, 16, 0, 0);
}

// Monotonic-counter grid barrier. All 256 blocks must call with identical increasing targets.
DEV void gridbar(unsigned* bar, unsigned target) {
  __syncthreads();
  if (threadIdx.x == 0) {
    __threadfence();                 // release: flush this XCD's L2
    atomicAdd(bar, 1u);
    while (__hip_atomic_load(bar, __ATOMIC_RELAXED, __HIP_MEMORY_SCOPE_AGENT) < target)
      __builtin_amdgcn_s_sleep(1);
  }
  __syncthreads();
  __threadfence();                   // acquire: invalidate L1/L2 so remote writes are visible
}

// ---------------- fp32 -> bf16 bulk convert (float4 at a time) ----------------
__global__ void k_f2bf(const float* __restrict__ in, ushort_t* __restrict__ out, int n4) {
  int i = blockIdx.x * blockDim.x + threadIdx.x;
  int st = gridDim.x * blockDim.x;
  for (; i < n4; i += st) {
    f32x4 v = *(const f32x4*)(in + (size_t)i * 4);
    u16x4 o;
    o[0] = f2bf(v[0]); o[1] = f2bf(v[1]); o[2] = f2bf(v[2]); o[3] = f2bf(v[3]);
    *(u16x4*)(out + (size_t)i * 4) = o;
  }
}

// ---------------- init GEMM (fp32 vector): P[m,r] = A'[m,:]·W4[r,512+:]  ----------------
// A' rows: m<4096 -> word_level_rep flat [4096,512]; m in [4096,4128) -> sentence_level_rep.
// Output: m<4096 -> P, else -> sp (the sentence half uses W4[r, 0:512]).
__global__ __launch_bounds__(256) void k_initP(
    const float* __restrict__ w, const float* __restrict__ sent,
    const float* __restrict__ W4, float* __restrict__ P, float* __restrict__ sp)
{
  __shared__ float As2[16 * 68];   // [k][m] transposed tiles, padded
  __shared__ float Bs2[16 * 68];   // [k][n]
  const int tid = threadIdx.x;
  const int m0 = blockIdx.x * 64, n0 = blockIdx.y * 64;
  const int tm = tid & 15, tn = tid >> 4;
  const bool sent_half = (m0 >= 4096);   // whole tile is sentence rows (4096 = 64*64 boundary)
  float acc[4][4];
#pragma unroll
  for (int i = 0; i < 4; i++)
#pragma unroll
    for (int j = 0; j < 4; j++) acc[i][j] = 0.f;

  for (int k0 = 0; k0 < 512; k0 += 16) {
#pragma unroll
    for (int i = 0; i < 4; i++) {
      int idx = i * 256 + tid;
      int r = idx >> 4, kk = idx & 15;
      int m = m0 + r;
      float va = 0.f;
      if (m < 4096) va = w[(size_t)m * 512 + k0 + kk];
      else if (m < 4128) va = sent[(m - 4096) * 512 + k0 + kk];
      As2[kk * 68 + r] = va;
      // sentence rows multiply against first half of W4 row; word rows against second half
      Bs2[kk * 68 + r] = W4[(size_t)(n0 + r) * 1024 + (sent_half ? 0 : 512) + k0 + kk];
    }
    __syncthreads();
#pragma unroll
    for (int k = 0; k < 16; k++) {
      f32x4 av = *(const f32x4*)&As2[k * 68 + tm * 4];
      f32x4 bv = *(const f32x4*)&Bs2[k * 68 + tn * 4];
#pragma unroll
      for (int i = 0; i < 4; i++)
#pragma unroll
        for (int j = 0; j < 4; j++) acc[i][j] = fmaf(av[i], bv[j], acc[i][j]);
    }
    __syncthreads();
  }
#pragma unroll
  for (int i = 0; i < 4; i++) {
    int m = m0 + tm * 4 + i;
    if (m >= 4128) continue;
#pragma unroll
    for (int j = 0; j < 4; j++) {
      int n = n0 + tn * 4 + j;
      if (m < 4096) P[(size_t)m * 512 + n] = acc[i][j];
      else sp[(m - 4096) * 512 + n] = acc[i][j];
    }
  }
}

// ---------------- persistent recurrence kernel: 256 blocks x 512 threads ----------------
// Phase A (all blocks): block (b=bid>>3, sg=bid&7) computes 16 attention scores (s-slice).
// Phase B (all blocks): softmax (redundant per sibling) + x-row slice via attn·P.
// Phase C (bid<128): block owns 4 h-rows; gates = [x;h] (K=1024) x Wcat[16] via MFMA,
//                    W frags persistent in registers; LSTM update; writes h (bf16) + A-matrix.
__global__ __launch_bounds__(512) void k_recur(
    const float* __restrict__ W2, const float* __restrict__ W_ih, const float* __restrict__ W_hh,
    const float* __restrict__ b_ih, const float* __restrict__ b_hh,
    const ushort_t* __restrict__ w_bf, const float* __restrict__ P, const float* __restrict__ sp,
    unsigned* __restrict__ bar, ushort_t* __restrict__ h_bf, ushort_t* __restrict__ x_bf,
    float* __restrict__ scores, ushort_t* __restrict__ h_A, float* __restrict__ h_fin)
{
  __shared__ ushort_t XHx[32 * 520];     // 33.3 KB: [batch][512 k] padded (+8) for bank spread
  __shared__ float gredf[4 * 512];       // 8 KB: MFMA partials (aliased as phase-B partials)
  __shared__ float gates_s[32 * 17];
  __shared__ float attn_s[128];
  __shared__ float sc_s[128];
  __shared__ float bias_s[16];
  __shared__ float cstate[128];          // [32 b][4 hr] fp32, persists across steps
  __shared__ float redm[2];

  const int bid = blockIdx.x, tid = threadIdx.x;
  const int wave = tid >> 6, lane = tid & 63;
  const int b_att = bid >> 3, sg = bid & 7;
  const int r0B = sg * 64;

  // persistent gate-weight fragments (n = gate*4 + hr; rows of Wcat, K=512 per matrix)
  bf16x8 bfr_ih[4], bfr_hh[4];
  if (bid < 128) {
    if (tid < 128) cstate[tid] = 0.f;
    if (tid < 16) {
      int n = tid;
      int grow = (n >> 2) * 512 + (bid << 2) + (n & 3);
      bias_s[n] = b_ih[grow] + b_hh[grow];
    }
    if (wave < 4) {
      int n = lane & 15, quad = lane >> 4;
      int grow = (n >> 2) * 512 + (bid << 2) + (n & 3);
#pragma unroll
      for (int ks = 0; ks < 4; ks++) {
        int kk = (wave * 4 + ks) * 32 + quad * 8;
        const float* pi = W_ih + (size_t)grow * 512 + kk;
        const float* ph = W_hh + (size_t)grow * 512 + kk;
#pragma unroll
        for (int j = 0; j < 8; j++) {
          bfr_ih[ks][j] = (short)f2bf(pi[j]);
          bfr_hh[ks][j] = (short)f2bf(ph[j]);
        }
      }
    }
  }

  // phase-A constants
  const int hoff = b_att * 512 + lane * 8;
  float w2v[8];
#pragma unroll
  for (int j = 0; j < 8; j++) w2v[j] = W2[lane * 8 + j];

  unsigned barcnt = 0;

  for (int t = 0; t < 64; t++) {
    const ushort_t* hprev = h_bf + ((t + 1) & 1) * 16384;
    ushort_t* hcur = h_bf + (t & 1) * 16384;

    // ---------------- phase A: scores[b, s-slice] ----------------
    {
      u16x8 hv = *(const u16x8*)(hprev + hoff);
      float hf[8];
#pragma unroll
      for (int j = 0; j < 8; j++) hf[j] = bf2f(hv[j]);
#pragma unroll
      for (int si = 0; si < 2; si++) {
        int s = sg * 16 + wave * 2 + si;
        u16x8 wv = *(const u16x8*)(w_bf + ((size_t)((b_att << 7) + s) << 9) + lane * 8);
        float acc = 0.f;
#pragma unroll
        for (int j = 0; j < 8; j++) {
          float v = bf2f(wv[j]) + hf[j];
          float e = __expf(2.f * v);
          acc = fmaf((e - 1.f) * fast_rcp(e + 1.f), w2v[j], acc);
        }
        acc = wave_sum(acc);
        if (lane == 0) scores[(b_att << 7) + s] = acc;
      }
    }
    barcnt++; gridbar(bar, barcnt * 256);

    // ---------------- phase B: softmax + x[b, r-slice] = tanh(sp + attn·P) ----------------
    {
      if (tid < 128) sc_s[tid] = scores[(b_att << 7) + tid];
      __syncthreads();
      if (wave == 0) {
        float m = fmaxf(sc_s[lane], sc_s[lane + 64]);
        m = wave_max(m);
        if (lane == 0) redm[0] = m;
      }
      __syncthreads();
      float mx = redm[0];
      if (wave == 0) {
        float e0 = __expf(sc_s[lane] - mx);
        float e1 = __expf(sc_s[lane + 64] - mx);
        attn_s[lane] = e0; attn_s[lane + 64] = e1;
        float ssum = wave_sum(e0 + e1);
        if (lane == 0) redm[1] = ssum;
      }
      __syncthreads();
      float inv = fast_rcp(redm[1]);
      int rl = tid & 63, s8 = tid >> 6;
      float part = 0.f;
      const float* Pp = P + ((size_t)((b_att << 7) + s8 * 16) << 9) + r0B + rl;
#pragma unroll
      for (int ss = 0; ss < 16; ss++) part = fmaf(attn_s[s8 * 16 + ss], Pp[(size_t)ss << 9], part);
      gredf[(s8 << 6) + rl] = part;
      __syncthreads();
      if (tid < 64) {
        float tot = 0.f;
#pragma unroll
        for (int kg = 0; kg < 8; kg++) tot += gredf[(kg << 6) + tid];
        tot = tot * inv + sp[b_att * 512 + r0B + tid];
        x_bf[b_att * 512 + r0B + tid] = f2bf(fast_tanh(tot));
      }
      __syncthreads();
    }
    barcnt++; gridbar(bar, barcnt * 256);

    // ---------------- phase C: gates + LSTM update (blocks 0..127) ----------------
    if (bid < 128) {
      f32x4 acc0 = {0.f, 0.f, 0.f, 0.f}, acc1 = {0.f, 0.f, 0.f, 0.f};
      // stage x -> XHx
#pragma unroll
      for (int i = 0; i < 4; i++) {
        int ci = i * 512 + tid;
        int bb = ci >> 6, j = (ci & 63) << 3;
        *(u16x8*)&XHx[bb * 520 + j] = *(const u16x8*)(x_bf + (ci << 3));
      }
      __syncthreads();
      if (wave < 4) {
#pragma unroll
        for (int ks = 0; ks < 4; ks++) {
          int kk = (wave * 4 + ks) * 32 + ((lane >> 4) << 3);
          bf16x8 a0 = *(const bf16x8*)&XHx[(lane & 15) * 520 + kk];
          bf16x8 a1 = *(const bf16x8*)&XHx[((lane & 15) + 16) * 520 + kk];
          acc0 = __builtin_amdgcn_mfma_f32_16x16x32_bf16(a0, bfr_ih[ks], acc0, 0, 0, 0);
          acc1 = __builtin_amdgcn_mfma_f32_16x16x32_bf16(a1, bfr_ih[ks], acc1, 0, 0, 0);
        }
      }
      __syncthreads();
      // stage h_prev -> XHx
#pragma unroll
      for (int i = 0; i < 4; i++) {
        int ci = i * 512 + tid;
        int bb = ci >> 6, j = (ci & 63) << 3;
        *(u16x8*)&XHx[bb * 520 + j] = *(const u16x8*)(hprev + (ci << 3));
      }
      __syncthreads();
      if (wave < 4) {
#pragma unroll
        for (int ks = 0; ks < 4; ks++) {
          int kk = (wave * 4 + ks) * 32 + ((lane >> 4) << 3);
          bf16x8 a0 = *(const bf16x8*)&XHx[(lane & 15) * 520 + kk];
          bf16x8 a1 = *(const bf16x8*)&XHx[((lane & 15) + 16) * 520 + kk];
          acc0 = __builtin_amdgcn_mfma_f32_16x16x32_bf16(a0, bfr_hh[ks], acc0, 0, 0, 0);
          acc1 = __builtin_amdgcn_mfma_f32_16x16x32_bf16(a1, bfr_hh[ks], acc1, 0, 0, 0);
        }
        *(f32x4*)&gredf[wave * 512 + lane * 4] = acc0;
        *(f32x4*)&gredf[wave * 512 + 256 + lane * 4] = acc1;
      }
      __syncthreads();
      {
        float v = gredf[tid] + gredf[512 + tid] + gredf[1024 + tid] + gredf[1536 + tid];
        int mt = tid >> 8, l = (tid >> 2) & 63, r = tid & 3;
        int batch = mt * 16 + ((l >> 4) << 2) + r;   // C/D: row=(lane>>4)*4+reg, col=lane&15
        int n = l & 15;
        gates_s[batch * 17 + n] = v + bias_s[n];
      }
      __syncthreads();
      if (tid < 128) {
        int bb = tid & 31, hr = tid >> 5;
        float gi = gates_s[bb * 17 + hr];
        float gf = gates_s[bb * 17 + 4 + hr];
        float gg = gates_s[bb * 17 + 8 + hr];
        float go = gates_s[bb * 17 + 12 + hr];
        float cold = cstate[(bb << 2) + hr];
        float cn = fast_sigm(gf) * cold + fast_sigm(gi) * fast_tanh(gg);
        float hn = fast_sigm(go) * fast_tanh(cn);
        cstate[(bb << 2) + hr] = cn;
        int R = (bid << 2) + hr;
        unsigned short hb = f2bf(hn);
        hcur[bb * 512 + R] = hb;
        h_A[(size_t)((bb << 6) + t) * 512 + R] = hb;   // A-matrix row m = b*64 + t
        if (t == 63) h_fin[bb * 512 + R] = hn;
      }
      __syncthreads();
    }
    barcnt++; gridbar(bar, barcnt * 256);
  }
}

// ---------------- big GEMM: C[2048,32000] = h_A[2048,512] x W_out_bf[32000,512]^T + b ----------------
__global__ __launch_bounds__(256) void k_gemm(
    const ushort_t* __restrict__ A, const ushort_t* __restrict__ Bw,
    const float* __restrict__ bias, float* __restrict__ C)
{
  __shared__ ushort_t As[128 * 64];
  __shared__ ushort_t Bs[128 * 64];
  const int tid = threadIdx.x;
  const int wave = tid >> 6, lane = tid & 63;
  const int ln = lane & 15, quad = lane >> 4;
  const int bm = blockIdx.x & 15, bn = blockIdx.x >> 4;   // m-inner => 16 blocks share B-tile in L2
  const int wm = wave & 1, wn = wave >> 1;

  f32x4 acc[4][4];
#pragma unroll
  for (int i = 0; i < 4; i++)
#pragma unroll
    for (int j = 0; j < 4; j++) { acc[i][j][0] = 0.f; acc[i][j][1] = 0.f; acc[i][j][2] = 0.f; acc[i][j][3] = 0.f; }

  for (int kt = 0; kt < 8; kt++) {
    const int k0 = kt * 64;
    // stage (XOR-swizzled 16B chunks): LDS[r][c] holds global chunk c^(r&7)
#pragma unroll
    for (int i = 0; i < 4; i++) {
      int s = i * 256 + tid;
      int r = s >> 3, c = s & 7;
      int cs = c ^ (r & 7);
      async_g2l(A + ((size_t)(bm * 128 + r) << 9) + k0 + (cs << 3), &As[s << 3]);
    }
#pragma unroll
    for (int i = 0; i < 4; i++) {
      int s = i * 256 + tid;
      int r = s >> 3, c = s & 7;
      int cs = c ^ (r & 7);
      async_g2l(Bw + ((size_t)(bn * 128 + r) << 9) + k0 + (cs << 3), &Bs[s << 3]);
    }
    __syncthreads();
#pragma unroll
    for (int ks = 0; ks < 2; ks++) {
      bf16x8 af[4], bfr[4];
      int cc = ks * 4 + quad;
#pragma unroll
      for (int f = 0; f < 4; f++) {
        int ra = wm * 64 + f * 16 + ln;
        af[f] = *(const bf16x8*)&As[((ra << 3) + (cc ^ (ra & 7))) << 3];
        int rb = wn * 64 + f * 16 + ln;
        bfr[f] = *(const bf16x8*)&Bs[((rb << 3) + (cc ^ (rb & 7))) << 3];
      }
#pragma unroll
      for (int mf = 0; mf < 4; mf++)
#pragma unroll
        for (int nf = 0; nf < 4; nf++)
          acc[mf][nf] = __builtin_amdgcn_mfma_f32_16x16x32_bf16(af[mf], bfr[nf], acc[mf][nf], 0, 0, 0);
    }
    __syncthreads();
  }
  // epilogue: C row m = b*64+t maps directly to out[b][t][:] (A was written in that order)
#pragma unroll
  for (int nf = 0; nf < 4; nf++) {
    int n = bn * 128 + wn * 64 + nf * 16 + ln;
    float bv = bias[n];
#pragma unroll
    for (int mf = 0; mf < 4; mf++) {
      int mbase = bm * 128 + wm * 64 + mf * 16 + (quad << 2);
#pragma unroll
      for (int r = 0; r < 4; r++)
        C[(size_t)(mbase + r) * 32000 + n] = acc[mf][nf][r] + bv;
    }
  }
}

// ---------------- launch ----------------
extern "C" void kernel_launch(void* const* d_in, const int* in_sizes, int n_in,
                              void* d_out, int out_size, void* d_ws, size_t ws_size,
                              hipStream_t stream) {
  const float* word  = (const float*)d_in[0];
  const float* sent  = (const float*)d_in[1];
  const float* W2    = (const float*)d_in[2];
  const float* W4    = (const float*)d_in[3];
  const float* W_ih  = (const float*)d_in[4];
  const float* W_hh  = (const float*)d_in[5];
  const float* b_ih  = (const float*)d_in[6];
  const float* b_hh  = (const float*)d_in[7];
  const float* W_out = (const float*)d_in[8];
  const float* b_out = (const float*)d_in[9];
  float* out = (float*)d_out;

  char* ws = (char*)d_ws;
  unsigned* bar     = (unsigned*)(ws + 0);
  ushort_t* h_bf    = (ushort_t*)(ws + 256);        // 2 x [32][512] bf16 (double buffered)
  ushort_t* x_bf    = (ushort_t*)(ws + 65792);      // [32][512] bf16
  float*    scores  = (float*)(ws + 98560);         // [32][128]
  float*    sp      = (float*)(ws + 114944);        // [32][512]
  float*    P       = (float*)(ws + 180480);        // [32][128][512] fp32
  ushort_t* w_bf    = (ushort_t*)(ws + 8569088);    // [32][128][512] bf16
  ushort_t* h_A     = (ushort_t*)(ws + 12763392);   // [2048][512] bf16 (m = b*64+t)
  ushort_t* Wout_bf = (ushort_t*)(ws + 14860544);   // [32000][512] bf16
  float* h_fin = out + 65536000;                    // total ws use ~45.4 MB

  hipMemsetAsync(ws, 0, 65792, stream);             // zero barrier + h0 buffers

  k_f2bf<<<2048, 256, 0, stream>>>(W_out, Wout_bf, 16384000 / 4);
  k_f2bf<<<512, 256, 0, stream>>>(word, w_bf, 2097152 / 4);
  k_initP<<<dim3(65, 8), 256, 0, stream>>>(word, sent, W4, P, sp);
  k_recur<<<256, 512, 0, stream>>>(W2, W_ih, W_hh, b_ih, b_hh, w_bf, P, sp,
                                   bar, h_bf, x_bf, scores, h_A, h_fin);
  k_gemm<<<4000, 256, 0, stream>>>(h_A, Wout_bf, b_out, out);
}

// Round 2
// 1687.612 us; speedup vs baseline: 5.3509x; 5.3509x over previous
//
#include <hip/hip_runtime.h>
#include <stdint.h>

typedef unsigned short ushort_t;
typedef unsigned long long ull_t;
typedef __attribute__((ext_vector_type(8))) short bf16x8;
typedef __attribute__((ext_vector_type(8))) unsigned short u16x8;
typedef __attribute__((ext_vector_type(4))) unsigned short u16x4;
typedef __attribute__((ext_vector_type(4))) float f32x4;

#define DEV static __device__ __forceinline__
#define SCOPE_AGENT __HIP_MEMORY_SCOPE_AGENT

DEV unsigned short f2bf(float f) {           // fp32 -> bf16 RNE
  unsigned u = __float_as_uint(f);
  u += 0x7FFFu + ((u >> 16) & 1u);
  return (unsigned short)(u >> 16);
}
DEV float bf2f(unsigned short h) { return __uint_as_float(((unsigned)h) << 16); }
DEV float fast_rcp(float x) { return __builtin_amdgcn_rcpf(x); }
DEV float fast_tanh(float x) { float e = __expf(2.f * x); return (e - 1.f) * fast_rcp(e + 1.f); }
DEV float fast_sigm(float x) { return fast_rcp(1.f + __expf(-x)); }

DEV float wave_sum(float v) {
#pragma unroll
  for (int d = 32; d > 0; d >>= 1) v += __shfl_xor(v, d, 64);
  return v;
}
DEV float wave_max(float v) {
#pragma unroll
  for (int d = 32; d > 0; d >>= 1) v = fmaxf(v, __shfl_xor(v, d, 64));
  return v;
}

DEV void async_g2l(const void* g, void* l) {   // 16B global -> LDS (dest = uniform base + lane*16)
  __builtin_amdgcn_global_load_lds((const __attribute__((address_space(1))) void*)g,
                                   (__attribute__((address_space(3))) void*)l, 16, 0, 0);
}

// ---- scoped-atomic communication helpers (sc1: bypass non-coherent L1/L2, coherent at IF$) ----
DEV unsigned ld_flag(unsigned* p) { return __hip_atomic_load(p, __ATOMIC_RELAXED, SCOPE_AGENT); }
DEV void st_flag(unsigned* p, unsigned v) { __hip_atomic_store(p, v, __ATOMIC_RELAXED, SCOPE_AGENT); }
DEV ull_t ld_u64(ull_t* p) { return __hip_atomic_load(p, __ATOMIC_RELAXED, SCOPE_AGENT); }
DEV void st_u64(ull_t* p, ull_t v) { __hip_atomic_store(p, v, __ATOMIC_RELAXED, SCOPE_AGENT); }
DEV void release_fence() { __builtin_amdgcn_s_waitcnt(0); }   // drain vm+lgkm: prior sc1 stores visible

// ---------------- fp32 -> bf16 bulk convert (float4 at a time) ----------------
__global__ void k_f2bf(const float* __restrict__ in, ushort_t* __restrict__ out, int n4) {
  int i = blockIdx.x * blockDim.x + threadIdx.x;
  int st = gridDim.x * blockDim.x;
  for (; i < n4; i += st) {
    f32x4 v = *(const f32x4*)(in + (size_t)i * 4);
    u16x4 o;
    o[0] = f2bf(v[0]); o[1] = f2bf(v[1]); o[2] = f2bf(v[2]); o[3] = f2bf(v[3]);
    *(u16x4*)(out + (size_t)i * 4) = o;
  }
}

// ---------------- init GEMM (fp32 vector): P[m,r] = A'[m,:]·W4[r,512+:] (bf16 out) ----------------
__global__ __launch_bounds__(256) void k_initP(
    const float* __restrict__ w, const float* __restrict__ sent,
    const float* __restrict__ W4, ushort_t* __restrict__ P, float* __restrict__ sp)
{
  __shared__ float As2[16 * 68];
  __shared__ float Bs2[16 * 68];
  const int tid = threadIdx.x;
  const int m0 = blockIdx.x * 64, n0 = blockIdx.y * 64;
  const int tm = tid & 15, tn = tid >> 4;
  const bool sent_half = (m0 >= 4096);
  float acc[4][4];
#pragma unroll
  for (int i = 0; i < 4; i++)
#pragma unroll
    for (int j = 0; j < 4; j++) acc[i][j] = 0.f;

  for (int k0 = 0; k0 < 512; k0 += 16) {
#pragma unroll
    for (int i = 0; i < 4; i++) {
      int idx = i * 256 + tid;
      int r = idx >> 4, kk = idx & 15;
      int m = m0 + r;
      float va = 0.f;
      if (m < 4096) va = w[(size_t)m * 512 + k0 + kk];
      else if (m < 4128) va = sent[(m - 4096) * 512 + k0 + kk];
      As2[kk * 68 + r] = va;
      Bs2[kk * 68 + r] = W4[(size_t)(n0 + r) * 1024 + (sent_half ? 0 : 512) + k0 + kk];
    }
    __syncthreads();
#pragma unroll
    for (int k = 0; k < 16; k++) {
      f32x4 av = *(const f32x4*)&As2[k * 68 + tm * 4];
      f32x4 bv = *(const f32x4*)&Bs2[k * 68 + tn * 4];
#pragma unroll
      for (int i = 0; i < 4; i++)
#pragma unroll
        for (int j = 0; j < 4; j++) acc[i][j] = fmaf(av[i], bv[j], acc[i][j]);
    }
    __syncthreads();
  }
#pragma unroll
  for (int i = 0; i < 4; i++) {
    int m = m0 + tm * 4 + i;
    if (m >= 4128) continue;
#pragma unroll
    for (int j = 0; j < 4; j++) {
      int n = n0 + tn * 4 + j;
      if (m < 4096) P[(size_t)m * 512 + n] = f2bf(acc[i][j]);
      else sp[(m - 4096) * 512 + n] = acc[i][j];
    }
  }
}

// ---------------- persistent recurrence: 160 blocks x 512 threads, flag-based sync ----------------
// Blocks 0..127  : gate blocks — own 4 h-rows (16 gate rows), weights persistent in registers.
// Blocks 128..159: attention blocks — one per batch, scores+softmax+x fully block-local.
// Handoffs per step: x (attn -> gates, xflag[32]) and h (gates -> attn+gates, hflag[128]).
// All cross-block data via relaxed agent-scope atomics (IF$-coherent, no fences, no L2 flushes).
struct GateS {
  ushort_t XHx[32 * 520];     // staged [batch][k] bf16, padded
  float gredf[8 * 512];       // per-wave MFMA partials
  float gates[32 * 17];
  float bias[16];
  float cstate[128];
  ushort_t hs16[128];
};
struct AttnS {
  float hs[512];
  float sps[512];
  float sc[128];
  float attw[128];
  float xpart[1024];
  ushort_t xs16[512];
};

__global__ __launch_bounds__(512) void k_recur(
    const float* __restrict__ W2, const float* __restrict__ W_ih, const float* __restrict__ W_hh,
    const float* __restrict__ b_ih, const float* __restrict__ b_hh,
    const ushort_t* __restrict__ w_bf, const ushort_t* __restrict__ P, const float* __restrict__ sp,
    unsigned* hflag, unsigned* xflag, ull_t* hbuf, ull_t* xbuf,
    ull_t* __restrict__ h_A, float* __restrict__ h_fin)
{
  __shared__ union { GateS g; AttnS a; } sm;
  const int bid = blockIdx.x, tid = threadIdx.x;
  const int wv = tid >> 6, lane = tid & 63;

  if (bid < 128) {
    // ================= gate block =================
    const int n16 = lane & 15, quad = lane >> 4;
    const int grow = (n16 >> 2) * 512 + (bid << 2) + (n16 & 3);
    if (tid < 128) sm.g.cstate[tid] = 0.f;
    if (tid < 16) {
      int gr = (tid >> 2) * 512 + (bid << 2) + (tid & 3);
      sm.g.bias[tid] = b_ih[gr] + b_hh[gr];
    }
    bf16x8 fih[2], fhh[2];
#pragma unroll
    for (int ks = 0; ks < 2; ks++) {
      int kk = (wv * 2 + ks) * 32 + quad * 8;
      const float* pi = W_ih + (size_t)grow * 512 + kk;
      const float* ph = W_hh + (size_t)grow * 512 + kk;
#pragma unroll
      for (int j = 0; j < 8; j++) {
        fih[ks][j] = (short)f2bf(pi[j]);
        fhh[ks][j] = (short)f2bf(ph[j]);
      }
    }
    __syncthreads();

    for (int t = 0; t < 64; t++) {
      // wait h[t-1] published (t=0: hbuf parity 1 is zeroed h0)
      if (t > 0 && tid < 128) {
        while (ld_flag(&hflag[tid]) < (unsigned)t) __builtin_amdgcn_s_sleep(2);
      }
      __syncthreads();
      // stage h[t-1] -> LDS
      ull_t* hsrc = hbuf + ((t + 1) & 1) * 4096;
#pragma unroll
      for (int i = 0; i < 8; i++) {
        int fl = i * 512 + tid;
        ull_t v = ld_u64(&hsrc[fl]);
        *(ull_t*)&sm.g.XHx[(fl >> 7) * 520 + (fl & 127) * 4] = v;
      }
      __syncthreads();
      f32x4 acc0 = {0.f, 0.f, 0.f, 0.f}, acc1 = {0.f, 0.f, 0.f, 0.f};
#pragma unroll
      for (int ks = 0; ks < 2; ks++) {      // W_hh half — overlaps attention's compute
        int kk = (wv * 2 + ks) * 32 + quad * 8;
        bf16x8 a0 = *(const bf16x8*)&sm.g.XHx[n16 * 520 + kk];
        bf16x8 a1 = *(const bf16x8*)&sm.g.XHx[(16 + n16) * 520 + kk];
        acc0 = __builtin_amdgcn_mfma_f32_16x16x32_bf16(a0, fhh[ks], acc0, 0, 0, 0);
        acc1 = __builtin_amdgcn_mfma_f32_16x16x32_bf16(a1, fhh[ks], acc1, 0, 0, 0);
      }
      // wait x[t]
      if (tid < 32) {
        while (ld_flag(&xflag[tid]) < (unsigned)(t + 1)) __builtin_amdgcn_s_sleep(2);
      }
      __syncthreads();
#pragma unroll
      for (int i = 0; i < 8; i++) {
        int fl = i * 512 + tid;
        ull_t v = ld_u64(&xbuf[fl]);
        *(ull_t*)&sm.g.XHx[(fl >> 7) * 520 + (fl & 127) * 4] = v;
      }
      __syncthreads();
#pragma unroll
      for (int ks = 0; ks < 2; ks++) {      // W_ih half
        int kk = (wv * 2 + ks) * 32 + quad * 8;
        bf16x8 a0 = *(const bf16x8*)&sm.g.XHx[n16 * 520 + kk];
        bf16x8 a1 = *(const bf16x8*)&sm.g.XHx[(16 + n16) * 520 + kk];
        acc0 = __builtin_amdgcn_mfma_f32_16x16x32_bf16(a0, fih[ks], acc0, 0, 0, 0);
        acc1 = __builtin_amdgcn_mfma_f32_16x16x32_bf16(a1, fih[ks], acc1, 0, 0, 0);
      }
      *(f32x4*)&sm.g.gredf[wv * 512 + lane * 4] = acc0;
      *(f32x4*)&sm.g.gredf[wv * 512 + 256 + lane * 4] = acc1;
      __syncthreads();
      {
        float v = 0.f;
#pragma unroll
        for (int k = 0; k < 8; k++) v += sm.g.gredf[k * 512 + tid];
        int mt = tid >> 8, l = (tid >> 2) & 63, r = tid & 3;
        int batch = mt * 16 + ((l >> 4) << 2) + r;   // C/D: row=(lane>>4)*4+reg, col=lane&15
        int n = l & 15;
        sm.g.gates[batch * 17 + n] = v + sm.g.bias[n];
      }
      __syncthreads();
      if (tid < 128) {
        int bb = tid & 31, hr = tid >> 5;
        float gi = sm.g.gates[bb * 17 + hr];
        float gf = sm.g.gates[bb * 17 + 4 + hr];
        float gg = sm.g.gates[bb * 17 + 8 + hr];
        float go = sm.g.gates[bb * 17 + 12 + hr];
        float cold = sm.g.cstate[(bb << 2) + hr];
        float cn = fast_sigm(gf) * cold + fast_sigm(gi) * fast_tanh(gg);
        float hn = fast_sigm(go) * fast_tanh(cn);
        sm.g.cstate[(bb << 2) + hr] = cn;
        sm.g.hs16[(bb << 2) + hr] = f2bf(hn);
        if (t == 63) h_fin[bb * 512 + (bid << 2) + hr] = hn;
      }
      __syncthreads();
      if (tid < 32) {
        ull_t v = *(const ull_t*)&sm.g.hs16[tid << 2];
        st_u64(&hbuf[(t & 1) * 4096 + tid * 128 + bid], v);   // h[t], parity-buffered
        h_A[((tid << 6) + t) * 128 + bid] = v;                // GEMM A row m=b*64+t (plain store)
        release_fence();
      }
      __syncthreads();
      if (tid == 0) st_flag(&hflag[bid], (unsigned)(t + 1));
    }
  } else {
    // ================= attention block (batch b) =================
    const int b = bid - 128;
    float w2v[8];
#pragma unroll
    for (int j = 0; j < 8; j++) w2v[j] = W2[lane * 8 + j];
    sm.a.sps[tid] = sp[b * 512 + tid];
    __syncthreads();

    for (int t = 0; t < 64; t++) {
      if (t > 0 && tid < 128) {
        while (ld_flag(&hflag[tid]) < (unsigned)t) __builtin_amdgcn_s_sleep(2);
      }
      __syncthreads();
      if (tid < 128) {
        ull_t v = ld_u64(&hbuf[((t + 1) & 1) * 4096 + b * 128 + tid]);
        sm.a.hs[tid * 4 + 0] = bf2f((unsigned short)v);
        sm.a.hs[tid * 4 + 1] = bf2f((unsigned short)(v >> 16));
        sm.a.hs[tid * 4 + 2] = bf2f((unsigned short)(v >> 32));
        sm.a.hs[tid * 4 + 3] = bf2f((unsigned short)(v >> 48));
      }
      __syncthreads();
      // scores: wave wv does s = wv*16 .. wv*16+15
      float hf[8];
#pragma unroll
      for (int j = 0; j < 8; j++) hf[j] = sm.a.hs[lane * 8 + j];
#pragma unroll
      for (int i = 0; i < 16; i++) {
        int s = wv * 16 + i;
        u16x8 wvv = *(const u16x8*)(w_bf + ((size_t)((b << 7) + s) << 9) + lane * 8);
        float acc = 0.f;
#pragma unroll
        for (int j = 0; j < 8; j++) {
          float v = bf2f(wvv[j]) + hf[j];
          float e = __expf(2.f * v);
          acc = fmaf((e - 1.f) * fast_rcp(e + 1.f), w2v[j], acc);
        }
        acc = wave_sum(acc);
        if (lane == 0) sm.a.sc[s] = acc;
      }
      __syncthreads();
      if (wv == 0) {   // softmax (wave 0)
        float a0 = sm.a.sc[lane], a1 = sm.a.sc[lane + 64];
        float m = wave_max(fmaxf(a0, a1));
        float e0 = __expf(a0 - m), e1 = __expf(a1 - m);
        float inv = fast_rcp(wave_sum(e0 + e1));
        sm.a.attw[lane] = e0 * inv;
        sm.a.attw[lane + 64] = e1 * inv;
      }
      __syncthreads();
      // x = tanh(sp + attn·P): threads split s in halves, 2 r per thread
      {
        int half = tid >> 8, rp = tid & 255;
        float a0 = 0.f, a1 = 0.f;
        const ushort_t* Pb = P + (((size_t)(b << 7) + half * 64) << 9) + rp * 2;
#pragma unroll 8
        for (int ss = 0; ss < 64; ss++) {
          float aw = sm.a.attw[half * 64 + ss];
          unsigned pv = *(const unsigned*)&Pb[(size_t)ss << 9];
          a0 = fmaf(aw, bf2f((unsigned short)pv), a0);
          a1 = fmaf(aw, bf2f((unsigned short)(pv >> 16)), a1);
        }
        sm.a.xpart[half * 512 + rp * 2] = a0;
        sm.a.xpart[half * 512 + rp * 2 + 1] = a1;
      }
      __syncthreads();
      {
        float xv = fast_tanh(sm.a.xpart[tid] + sm.a.xpart[512 + tid] + sm.a.sps[tid]);
        sm.a.xs16[tid] = f2bf(xv);
      }
      __syncthreads();
      if (tid < 128) {
        ull_t v = *(const ull_t*)&sm.a.xs16[tid << 2];
        st_u64(&xbuf[b * 128 + tid], v);
        release_fence();
      }
      __syncthreads();
      if (tid == 0) st_flag(&xflag[b], (unsigned)(t + 1));
    }
  }
}

// ---------------- big GEMM: C[2048,32000] = h_A[2048,512] x W_out_bf[32000,512]^T + b ----------------
__global__ __launch_bounds__(256) void k_gemm(
    const ushort_t* __restrict__ A, const ushort_t* __restrict__ Bw,
    const float* __restrict__ bias, float* __restrict__ C)
{
  __shared__ ushort_t As[128 * 64];
  __shared__ ushort_t Bs[128 * 64];
  const int tid = threadIdx.x;
  const int wave = tid >> 6, lane = tid & 63;
  const int ln = lane & 15, quad = lane >> 4;
  const int bm = blockIdx.x & 15, bn = blockIdx.x >> 4;
  const int wm = wave & 1, wn = wave >> 1;

  f32x4 acc[4][4];
#pragma unroll
  for (int i = 0; i < 4; i++)
#pragma unroll
    for (int j = 0; j < 4; j++) { acc[i][j][0] = 0.f; acc[i][j][1] = 0.f; acc[i][j][2] = 0.f; acc[i][j][3] = 0.f; }

  for (int kt = 0; kt < 8; kt++) {
    const int k0 = kt * 64;
#pragma unroll
    for (int i = 0; i < 4; i++) {
      int s = i * 256 + tid;
      int r = s >> 3, c = s & 7;
      int cs = c ^ (r & 7);
      async_g2l(A + ((size_t)(bm * 128 + r) << 9) + k0 + (cs << 3), &As[s << 3]);
    }
#pragma unroll
    for (int i = 0; i < 4; i++) {
      int s = i * 256 + tid;
      int r = s >> 3, c = s & 7;
      int cs = c ^ (r & 7);
      async_g2l(Bw + ((size_t)(bn * 128 + r) << 9) + k0 + (cs << 3), &Bs[s << 3]);
    }
    __syncthreads();
#pragma unroll
    for (int ks = 0; ks < 2; ks++) {
      bf16x8 af[4], bfr[4];
      int cc = ks * 4 + quad;
#pragma unroll
      for (int f = 0; f < 4; f++) {
        int ra = wm * 64 + f * 16 + ln;
        af[f] = *(const bf16x8*)&As[((ra << 3) + (cc ^ (ra & 7))) << 3];
        int rb = wn * 64 + f * 16 + ln;
        bfr[f] = *(const bf16x8*)&Bs[((rb << 3) + (cc ^ (rb & 7))) << 3];
      }
#pragma unroll
      for (int mf = 0; mf < 4; mf++)
#pragma unroll
        for (int nf = 0; nf < 4; nf++)
          acc[mf][nf] = __builtin_amdgcn_mfma_f32_16x16x32_bf16(af[mf], bfr[nf], acc[mf][nf], 0, 0, 0);
    }
    __syncthreads();
  }
#pragma unroll
  for (int nf = 0; nf < 4; nf++) {
    int n = bn * 128 + wn * 64 + nf * 16 + ln;
    float bv = bias[n];
#pragma unroll
    for (int mf = 0; mf < 4; mf++) {
      int mbase = bm * 128 + wm * 64 + mf * 16 + (quad << 2);
#pragma unroll
      for (int r = 0; r < 4; r++)
        C[(size_t)(mbase + r) * 32000 + n] = acc[mf][nf][r] + bv;
    }
  }
}

// ---------------- launch ----------------
extern "C" void kernel_launch(void* const* d_in, const int* in_sizes, int n_in,
                              void* d_out, int out_size, void* d_ws, size_t ws_size,
                              hipStream_t stream) {
  const float* word  = (const float*)d_in[0];
  const float* sent  = (const float*)d_in[1];
  const float* W2    = (const float*)d_in[2];
  const float* W4    = (const float*)d_in[3];
  const float* W_ih  = (const float*)d_in[4];
  const float* W_hh  = (const float*)d_in[5];
  const float* b_ih  = (const float*)d_in[6];
  const float* b_hh  = (const float*)d_in[7];
  const float* W_out = (const float*)d_in[8];
  const float* b_out = (const float*)d_in[9];
  float* out = (float*)d_out;

  char* ws = (char*)d_ws;
  unsigned* hflag   = (unsigned*)(ws + 0);          // [128]
  unsigned* xflag   = (unsigned*)(ws + 512);        // [32]
  ull_t*    hbuf    = (ull_t*)(ws + 1024);          // 2 x [32][512] bf16 (parity)
  ull_t*    xbuf    = (ull_t*)(ws + 66560);         // [32][512] bf16
  float*    sp      = (float*)(ws + 99328);         // [32][512] fp32
  ushort_t* P       = (ushort_t*)(ws + 164864);     // [32][128][512] bf16
  ushort_t* w_bf    = (ushort_t*)(ws + 4359168);    // [32][128][512] bf16
  ull_t*    h_A     = (ull_t*)(ws + 8553472);       // [2048][512] bf16 (m = b*64+t)
  ushort_t* Wout_bf = (ushort_t*)(ws + 10650624);   // [32000][512] bf16 -> ends 43,418,624
  float* h_fin = out + 65536000;

  hipMemsetAsync(ws, 0, 66560, stream);             // zero flags + both h parity buffers

  k_f2bf<<<2048, 256, 0, stream>>>(W_out, Wout_bf, 16384000 / 4);
  k_f2bf<<<512, 256, 0, stream>>>(word, w_bf, 2097152 / 4);
  k_initP<<<dim3(65, 8), 256, 0, stream>>>(word, sent, W4, P, sp);
  k_recur<<<160, 512, 0, stream>>>(W2, W_ih, W_hh, b_ih, b_hh, w_bf, P, sp,
                                   hflag, xflag, hbuf, xbuf, h_A, h_fin);
  k_gemm<<<4000, 256, 0, stream>>>((const ushort_t*)h_A, Wout_bf, b_out, out);
}